// Round 10
// baseline (312.588 us; speedup 1.0000x reference)
//
#include <hip/hip_runtime.h>

#define Bn 4
#define Cn 64
#define Hn 128
#define Wn 128
#define HWn (Hn*Wn)          // 16384
#define NPIX (Bn*HWn)        // 65536
#define KKn 9
#define NOFF 18
#define EPSf 1e-5f

// ws layout (float-word offsets)
#define OFF_DWT   0u              // f32 [p][c], 4194304 words
#define OFF_XTH   4194304u        // bf16 [p][c], 4194304 ushorts = 2097152 words
#define OFF_GEOM  6291456u        // f32 [kk][p][2], 1179648 words
#define OFF_WT    7471104u        // bf16 [kk][o][c], 73728 ushorts = 36864 words
#define OFF_SSUM  7507968u
#define OFF_SSQ   7508032u
#define OFF_SCALE 7508096u
#define OFF_SHIFT 7508160u

typedef __attribute__((ext_vector_type(8))) short short8v;
typedef __attribute__((ext_vector_type(8))) unsigned short ushort8v;
typedef __attribute__((ext_vector_type(4))) float float4v;

// round-to-nearest-even f32 -> bf16 bits
__device__ __forceinline__ unsigned short f2bf(float f) {
  unsigned u = __builtin_bit_cast(unsigned, f);
  u += 0x7fffu + ((u >> 16) & 1u);
  return (unsigned short)(u >> 16);
}
__device__ __forceinline__ float b2f(unsigned short u) {
  return __builtin_bit_cast(float, ((unsigned)u) << 16);
}

// ---------------------------------------------------------------------------
// K1v3: depthwise 3x3 conv + bias -> DWT (NHWC f32) and x -> XTH (NHWC bf16).
// 1024 blocks x 256 threads; thread = (px in 64-px slab, 16-ch group) so the
// grid is 4096 waves (4/SIMD, was 1/SIMD). LDS transpose, contiguous flushes.
__global__ __launch_bounds__(256) void k1_dw_t3(
    const float* __restrict__ x, const float* __restrict__ dw_w,
    const float* __restrict__ dw_b, unsigned short* __restrict__ XTH,
    float* __restrict__ DWT)
{
  __shared__ float lds_dw[64][65];
  __shared__ float lds_xt[64][65];
  const int t = threadIdx.x;
  const int pxl = t & 63;
  const int cg = t >> 6;                 // 0..3 -> 16-channel group
  const int p = blockIdx.x * 64 + pxl;   // 64 px per block, rows not straddled
  const int b = p >> 14; const int sp = p & 16383;
  const int h = sp >> 7; const int w = sp & 127;

  int so[9]; float mval[9];
  #pragma unroll
  for (int tt = 0; tt < 9; tt++) {
    int dy = tt / 3 - 1, dx = tt % 3 - 1;
    int hh = h + dy, ww = w + dx;
    bool v = (hh >= 0) && (hh < Hn) && (ww >= 0) && (ww < Wn);
    int hc = v ? hh : h; int wc = v ? ww : w;
    so[tt] = hc * Wn + wc;
    mval[tt] = v ? 1.f : 0.f;
  }
  const float* xb = x + (size_t)b * Cn * HWn;

  #pragma unroll
  for (int j = 0; j < 16; j++) {
    int c = cg * 16 + j;
    const float* xc = xb + (size_t)c * HWn;
    float acc = dw_b[c];
    #pragma unroll
    for (int tt = 0; tt < 9; tt++)
      acc += (mval[tt] * xc[so[tt]]) * dw_w[c * 9 + tt];
    lds_dw[pxl][c] = acc;
    lds_xt[pxl][c] = xc[sp];
  }
  __syncthreads();

  // DWT flush: pass k covers 16 px, 16 lanes/px * float4 -> 256B/px contiguous
  #pragma unroll
  for (int k = 0; k < 4; k++) {
    int px_l = k * 16 + (t >> 4);
    int c_l  = (t & 15) * 4;
    float4 v = *(float4*)&lds_dw[px_l][c_l];
    size_t pp = (size_t)blockIdx.x * 64 + px_l;
    *(float4*)&DWT[pp * 64 + c_l] = v;
  }
  // XTH flush: pass k covers 32 px, 8 lanes/px * uint4 -> 128B/px contiguous
  #pragma unroll
  for (int k = 0; k < 2; k++) {
    int px_l = k * 32 + (t >> 3);
    int cg8  = (t & 7) * 8;
    unsigned pk[4];
    #pragma unroll
    for (int j = 0; j < 4; j++) {
      unsigned short lo = f2bf(lds_xt[px_l][cg8 + 2 * j]);
      unsigned short hi = f2bf(lds_xt[px_l][cg8 + 2 * j + 1]);
      pk[j] = (unsigned)lo | ((unsigned)hi << 16);
    }
    size_t pp = (size_t)blockIdx.x * 64 + px_l;
    *(uint4*)&XTH[pp * 64 + cg8] = make_uint4(pk[0], pk[1], pk[2], pk[3]);
  }
}

// ---------------------------------------------------------------------------
// K_stats: per-channel sum / sumsq over DWT (1024 blocks -> 4 waves/SIMD)
__global__ __launch_bounds__(256) void k_stats(const float* __restrict__ DWT,
    float* __restrict__ ssum, float* __restrict__ ssq)
{
  int t = threadIdx.x; int c = t & 63; int g = t >> 6;
  float s = 0.f, q = 0.f;
  for (int p = blockIdx.x * 4 + g; p < NPIX; p += gridDim.x * 4) {
    float v = DWT[(size_t)p * 64 + c];
    s += v; q += v * v;
  }
  __shared__ float ls[2][256];
  ls[0][t] = s; ls[1][t] = q;
  __syncthreads();
  if (t < 64) {
    float s0 = ls[0][t] + ls[0][t + 64] + ls[0][t + 128] + ls[0][t + 192];
    float q0 = ls[1][t] + ls[1][t + 64] + ls[1][t + 128] + ls[1][t + 192];
    atomicAdd(&ssum[t], s0);
    atomicAdd(&ssq[t], q0);
  }
}

// ---------------------------------------------------------------------------
__global__ void k2_finalize(const float* __restrict__ ssum, const float* __restrict__ ssq,
    const float* __restrict__ gamma, const float* __restrict__ beta,
    float* __restrict__ scale, float* __restrict__ shift)
{
  int c = threadIdx.x;
  float n = (float)NPIX;
  float mean = ssum[c] / n;
  float var = ssq[c] / n - mean * mean;
  float sc = gamma[c] * rsqrtf(var + EPSf);
  scale[c] = sc;
  shift[c] = beta[c] - mean * sc;
}

// ---------------------------------------------------------------------------
__global__ __launch_bounds__(256) void k_wt(const float* __restrict__ dwf,
                                            unsigned short* __restrict__ WT2)
{
  int t = blockIdx.x * 256 + threadIdx.x;
  if (t >= 64 * 64 * 9) return;
  int c = t & 63; int o = (t >> 6) & 63; int kk = t >> 12;
  WT2[t] = f2bf(dwf[(o * 64 + c) * 9 + kk]);
}

// ---------------------------------------------------------------------------
__global__ __launch_bounds__(256) void k3_offsets(const float* __restrict__ DWT,
    const float* __restrict__ scale, const float* __restrict__ shift,
    const float* __restrict__ pw_w, const float* __restrict__ pw_b,
    float* __restrict__ GEOM2)
{
  int p = blockIdx.x * 256 + threadIdx.x;
  int sp = p & 16383; int h = sp >> 7; int w = sp & 127;
  float off[NOFF];
  #pragma unroll
  for (int o = 0; o < NOFF; o++) off[o] = pw_b[o];
  const float4* dp = (const float4*)(DWT + (size_t)p * 64);
  #pragma unroll
  for (int c4 = 0; c4 < 16; c4++) {
    float4 d = dp[c4];
    int c = c4 * 4;
    float x0 = d.x * scale[c]     + shift[c];
    float x1 = d.y * scale[c + 1] + shift[c + 1];
    float x2 = d.z * scale[c + 2] + shift[c + 2];
    float x3 = d.w * scale[c + 3] + shift[c + 3];
    #pragma unroll
    for (int o = 0; o < NOFF; o++) {
      const float* pw = pw_w + o * 64 + c;
      off[o] += pw[0] * x0 + pw[1] * x1 + pw[2] * x2 + pw[3] * x3;
    }
  }
  #pragma unroll
  for (int kk = 0; kk < KKn; kk++) {
    float py = (float)h - 1.f + (float)(kk / 3) + off[2 * kk];
    float px = (float)w - 1.f + (float)(kk % 3) + off[2 * kk + 1];
    float2* g = (float2*)(GEOM2 + ((size_t)kk * NPIX + p) * 2);
    *g = make_float2(py, px);
  }
}

// ---------------------------------------------------------------------------
// K4v3 (MFMA, bf16 gathers, kk-unrolled x3 for load/blend overlap).
// 2048 blocks x 32 px, 4 waves each own 16 o. XCD-bijective swizzle.
__global__ __launch_bounds__(256) void k4_mfma3(
    const unsigned short* __restrict__ XTH, const float* __restrict__ DWT,
    const float* __restrict__ GEOM2, const unsigned short* __restrict__ WT2,
    const float* __restrict__ scale, const float* __restrict__ shift,
    const float* __restrict__ deform_b, const float* __restrict__ skip_scale,
    float* __restrict__ out)
{
  const int tid = threadIdx.x;
  const int lane = tid & 63;
  const int wv = tid >> 6;
  const int l15 = lane & 15;
  const int lg = lane >> 4;
  const int bid = blockIdx.x;
  const int swz = (bid & 7) * 256 + (bid >> 3);   // 2048 % 8 == 0 -> bijective
  const int p0 = swz * 32;
  const int b = p0 >> 14;
  const int obase = wv * 16;
  const int c8 = lg * 8;

  float4v acc[2];
  acc[0] = (float4v){0.f, 0.f, 0.f, 0.f};
  acc[1] = (float4v){0.f, 0.f, 0.f, 0.f};

  const unsigned short* xb = XTH + (size_t)b * HWn * 64;

  #pragma unroll 3
  for (int kk = 0; kk < KKn; kk++) {
    const unsigned short* wtk = WT2 + ((size_t)kk * 64 + obase + l15) * 64;
    short8v bf0 = *(const short8v*)(wtk + c8);
    short8v bf1 = *(const short8v*)(wtk + 32 + c8);

    #pragma unroll
    for (int mt = 0; mt < 2; mt++) {
      int p = p0 + mt * 16 + l15;
      float2 g = *(const float2*)(GEOM2 + ((size_t)kk * NPIX + p) * 2);
      float py = g.x, px = g.y;
      float y0f = floorf(py), x0f = floorf(px);
      float wy = py - y0f, wx = px - x0f;
      int y0 = (int)y0f, x0i = (int)x0f;
      int y1 = y0 + 1, x1i = x0i + 1;
      bool vy0 = (y0 >= 0) && (y0 < Hn), vy1 = (y1 >= 0) && (y1 < Hn);
      bool vx0 = (x0i >= 0) && (x0i < Wn), vx1 = (x1i >= 0) && (x1i < Wn);
      int y0c = vy0 ? y0 : 0, y1c = vy1 ? y1 : 0;
      int x0c = vx0 ? x0i : 0, x1c = vx1 ? x1i : 0;
      float m00 = (vy0 && vx0) ? (1.f - wy) * (1.f - wx) : 0.f;
      float m01 = (vy0 && vx1) ? (1.f - wy) * wx : 0.f;
      float m10 = (vy1 && vx0) ? wy * (1.f - wx) : 0.f;
      float m11 = (vy1 && vx1) ? wy * wx : 0.f;

      const unsigned short* b00 = xb + (size_t)((y0c * Wn + x0c) * 64);
      const unsigned short* b01 = xb + (size_t)((y0c * Wn + x1c) * 64);
      const unsigned short* b10 = xb + (size_t)((y1c * Wn + x0c) * 64);
      const unsigned short* b11 = xb + (size_t)((y1c * Wn + x1c) * 64);

      // chunk 0: channels [c8, c8+8)
      {
        ushort8v u00 = *(const ushort8v*)(b00 + c8);
        ushort8v u01 = *(const ushort8v*)(b01 + c8);
        ushort8v u10 = *(const ushort8v*)(b10 + c8);
        ushort8v u11 = *(const ushort8v*)(b11 + c8);
        short8v af;
        #pragma unroll
        for (int j = 0; j < 8; j++) {
          float s = b2f(u00[j]) * m00 + b2f(u01[j]) * m01 +
                    b2f(u10[j]) * m10 + b2f(u11[j]) * m11;
          af[j] = (short)f2bf(s);
        }
        acc[mt] = __builtin_amdgcn_mfma_f32_16x16x32_bf16(af, bf0, acc[mt], 0, 0, 0);
      }
      // chunk 1: channels [32+c8, 32+c8+8)
      {
        ushort8v u00 = *(const ushort8v*)(b00 + 32 + c8);
        ushort8v u01 = *(const ushort8v*)(b01 + 32 + c8);
        ushort8v u10 = *(const ushort8v*)(b10 + 32 + c8);
        ushort8v u11 = *(const ushort8v*)(b11 + 32 + c8);
        short8v af;
        #pragma unroll
        for (int j = 0; j < 8; j++) {
          float s = b2f(u00[j]) * m00 + b2f(u01[j]) * m01 +
                    b2f(u10[j]) * m10 + b2f(u11[j]) * m11;
          af[j] = (short)f2bf(s);
        }
        acc[mt] = __builtin_amdgcn_mfma_f32_16x16x32_bf16(af, bf1, acc[mt], 0, 0, 0);
      }
    }
  }

  // Epilogue
  float sk = skip_scale[0];
  int o = obase + l15;
  float sc = scale[o], sh = shift[o], db = deform_b[o];
  float* outb = out + ((size_t)(b * 64 + o)) * HWn;
  #pragma unroll
  for (int mt = 0; mt < 2; mt++) {
    #pragma unroll
    for (int r = 0; r < 4; r++) {
      int p = p0 + mt * 16 + lg * 4 + r;
      int sp = p & 16383;
      float dv = DWT[(size_t)p * 64 + o];
      float xv = b2f(XTH[(size_t)p * 64 + o]);
      outb[sp] = acc[mt][r] + db + dv * sc + sh + xv * sk;
    }
  }
}

// ---------------------------------------------------------------------------
extern "C" void kernel_launch(void* const* d_in, const int* in_sizes, int n_in,
                              void* d_out, int out_size, void* d_ws, size_t ws_size,
                              hipStream_t stream)
{
  const float* x        = (const float*)d_in[0];
  const float* dw_w     = (const float*)d_in[1];
  const float* dw_b     = (const float*)d_in[2];
  const float* bn_gamma = (const float*)d_in[3];
  const float* bn_beta  = (const float*)d_in[4];
  const float* pw_w     = (const float*)d_in[5];
  const float* pw_b     = (const float*)d_in[6];
  const float* skip     = (const float*)d_in[7];
  const float* deform_w = (const float*)d_in[8];
  const float* deform_b = (const float*)d_in[9];
  float* out = (float*)d_out;
  float* ws  = (float*)d_ws;

  unsigned short* XTH = (unsigned short*)(ws + OFF_XTH);
  unsigned short* WT2 = (unsigned short*)(ws + OFF_WT);

  hipMemsetAsync(ws + OFF_SSUM, 0, 2 * 64 * sizeof(float), stream);

  k_wt<<<144, 256, 0, stream>>>(deform_w, WT2);
  k1_dw_t3<<<1024, 256, 0, stream>>>(x, dw_w, dw_b, XTH, ws + OFF_DWT);
  k_stats<<<1024, 256, 0, stream>>>(ws + OFF_DWT, ws + OFF_SSUM, ws + OFF_SSQ);
  k2_finalize<<<1, 64, 0, stream>>>(ws + OFF_SSUM, ws + OFF_SSQ, bn_gamma, bn_beta,
                                    ws + OFF_SCALE, ws + OFF_SHIFT);
  k3_offsets<<<256, 256, 0, stream>>>(ws + OFF_DWT, ws + OFF_SCALE, ws + OFF_SHIFT,
                                      pw_w, pw_b, ws + OFF_GEOM);
  k4_mfma3<<<2048, 256, 0, stream>>>(XTH, ws + OFF_DWT, ws + OFF_GEOM, WT2,
                                     ws + OFF_SCALE, ws + OFF_SHIFT,
                                     deform_b, skip, out);
}

// Round 11
// 217.584 us; speedup vs baseline: 1.4366x; 1.4366x over previous
//
#include <hip/hip_runtime.h>

#define Bn 4
#define Cn 64
#define Hn 128
#define Wn 128
#define HWn (Hn*Wn)          // 16384
#define NPIX (Bn*HWn)        // 65536
#define KKn 9
#define NOFF 18
#define EPSf 1e-5f

// ws layout (float-word offsets)
#define OFF_DWT   0u              // f32 [p][c], 4194304 words
#define OFF_XTH   4194304u        // bf16 [p][c], 2097152 words
#define OFF_GEOM  6291456u        // f32 [kk][p][2], 1179648 words
#define OFF_WT    7471104u        // bf16 [kk][o][c], 36864 words
#define OFF_SSUM  7507968u
#define OFF_SSQ   7508032u

typedef __attribute__((ext_vector_type(8))) short short8v;
typedef __attribute__((ext_vector_type(8))) unsigned short ushort8v;
typedef __attribute__((ext_vector_type(4))) float float4v;

__device__ __forceinline__ unsigned short f2bf(float f) {
  unsigned u = __builtin_bit_cast(unsigned, f);
  u += 0x7fffu + ((u >> 16) & 1u);
  return (unsigned short)(u >> 16);
}
__device__ __forceinline__ float b2f(unsigned short u) {
  return __builtin_bit_cast(float, ((unsigned)u) << 16);
}

// compute 4 corner base pointers + masks from a sample coordinate
#define MKADDR(GG, B00, B01, B10, B11, M00, M01, M10, M11)                    \
  {                                                                           \
    float py_ = (GG).x, px_ = (GG).y;                                         \
    float y0f_ = floorf(py_), x0f_ = floorf(px_);                             \
    float wy_ = py_ - y0f_, wx_ = px_ - x0f_;                                 \
    int y0_ = (int)y0f_, x0_ = (int)x0f_;                                     \
    int y1_ = y0_ + 1, x1_ = x0_ + 1;                                         \
    bool vy0_ = (y0_ >= 0) && (y0_ < Hn), vy1_ = (y1_ >= 0) && (y1_ < Hn);    \
    bool vx0_ = (x0_ >= 0) && (x0_ < Wn), vx1_ = (x1_ >= 0) && (x1_ < Wn);    \
    int y0c_ = vy0_ ? y0_ : 0, y1c_ = vy1_ ? y1_ : 0;                         \
    int x0c_ = vx0_ ? x0_ : 0, x1c_ = vx1_ ? x1_ : 0;                         \
    M00 = (vy0_ && vx0_) ? (1.f - wy_) * (1.f - wx_) : 0.f;                   \
    M01 = (vy0_ && vx1_) ? (1.f - wy_) * wx_ : 0.f;                           \
    M10 = (vy1_ && vx0_) ? wy_ * (1.f - wx_) : 0.f;                           \
    M11 = (vy1_ && vx1_) ? wy_ * wx_ : 0.f;                                   \
    B00 = xb + (size_t)((y0c_ * Wn + x0c_) * 64);                             \
    B01 = xb + (size_t)((y0c_ * Wn + x1c_) * 64);                             \
    B10 = xb + (size_t)((y1c_ * Wn + x0c_) * 64);                             \
    B11 = xb + (size_t)((y1c_ * Wn + x1c_) * 64);                             \
  }

// ---------------------------------------------------------------------------
// K1v4: depthwise 3x3 + bias -> DWT f32 / XTH bf16 (NHWC), BN stats fused.
__global__ __launch_bounds__(256) void k1_dw_t4(
    const float* __restrict__ x, const float* __restrict__ dw_w,
    const float* __restrict__ dw_b, unsigned short* __restrict__ XTH,
    float* __restrict__ DWT, float* __restrict__ ssum, float* __restrict__ ssq)
{
  __shared__ float lds_dw[64][65];
  __shared__ float lds_xt[64][65];
  const int t = threadIdx.x;
  const int pxl = t & 63;
  const int cg = t >> 6;
  const int p = blockIdx.x * 64 + pxl;
  const int b = p >> 14; const int sp = p & 16383;
  const int h = sp >> 7; const int w = sp & 127;

  int so[9]; float mval[9];
  #pragma unroll
  for (int tt = 0; tt < 9; tt++) {
    int dy = tt / 3 - 1, dx = tt % 3 - 1;
    int hh = h + dy, ww = w + dx;
    bool v = (hh >= 0) && (hh < Hn) && (ww >= 0) && (ww < Wn);
    int hc = v ? hh : h; int wc = v ? ww : w;
    so[tt] = hc * Wn + wc;
    mval[tt] = v ? 1.f : 0.f;
  }
  const float* xb = x + (size_t)b * Cn * HWn;

  #pragma unroll
  for (int j = 0; j < 16; j++) {
    int c = cg * 16 + j;
    const float* xc = xb + (size_t)c * HWn;
    float acc = dw_b[c];
    #pragma unroll
    for (int tt = 0; tt < 9; tt++)
      acc += (mval[tt] * xc[so[tt]]) * dw_w[c * 9 + tt];
    lds_dw[pxl][c] = acc;
    lds_xt[pxl][c] = xc[sp];
  }
  __syncthreads();

  // DWT flush: 16 px/pass, 16 lanes/px * float4
  #pragma unroll
  for (int k = 0; k < 4; k++) {
    int px_l = k * 16 + (t >> 4);
    int c_l  = (t & 15) * 4;
    float4 v = *(float4*)&lds_dw[px_l][c_l];
    size_t pp = (size_t)blockIdx.x * 64 + px_l;
    *(float4*)&DWT[pp * 64 + c_l] = v;
  }
  // XTH flush: 32 px/pass, 8 lanes/px * uint4
  #pragma unroll
  for (int k = 0; k < 2; k++) {
    int px_l = k * 32 + (t >> 3);
    int cg8  = (t & 7) * 8;
    unsigned pk[4];
    #pragma unroll
    for (int j = 0; j < 4; j++) {
      unsigned short lo = f2bf(lds_xt[px_l][cg8 + 2 * j]);
      unsigned short hi = f2bf(lds_xt[px_l][cg8 + 2 * j + 1]);
      pk[j] = (unsigned)lo | ((unsigned)hi << 16);
    }
    size_t pp = (size_t)blockIdx.x * 64 + px_l;
    *(uint4*)&XTH[pp * 64 + cg8] = make_uint4(pk[0], pk[1], pk[2], pk[3]);
  }

  // fused BN stats: thread (c = t&63, grp = t>>6) sums 16 px
  int cc = t & 63, grp = t >> 6;
  float s = 0.f, q = 0.f;
  #pragma unroll
  for (int i = 0; i < 16; i++) {
    float v = lds_dw[grp * 16 + i][cc];
    s += v; q += v * v;
  }
  __syncthreads();                       // XTH-flush reads of lds_xt done
  float* scratch = &lds_xt[0][0];
  scratch[t] = s; scratch[256 + t] = q;
  __syncthreads();
  if (t < 64) {
    float s0 = scratch[t] + scratch[t + 64] + scratch[t + 128] + scratch[t + 192];
    float q0 = scratch[256 + t] + scratch[256 + t + 64] +
               scratch[256 + t + 128] + scratch[256 + t + 192];
    atomicAdd(&ssum[t], s0);
    atomicAdd(&ssq[t], q0);
  }
}

// ---------------------------------------------------------------------------
__global__ __launch_bounds__(256) void k_wt(const float* __restrict__ dwf,
                                            unsigned short* __restrict__ WT2)
{
  int t = blockIdx.x * 256 + threadIdx.x;
  if (t >= 64 * 64 * 9) return;
  int c = t & 63; int o = (t >> 6) & 63; int kk = t >> 12;
  WT2[t] = f2bf(dwf[(o * 64 + c) * 9 + kk]);
}

// ---------------------------------------------------------------------------
// K3v2: BN finalize fused in head; offsets -> GEOM2[kk][p][2]
__global__ __launch_bounds__(256) void k3_offsets2(const float* __restrict__ DWT,
    const float* __restrict__ ssum, const float* __restrict__ ssq,
    const float* __restrict__ gamma, const float* __restrict__ beta,
    const float* __restrict__ pw_w, const float* __restrict__ pw_b,
    float* __restrict__ GEOM2)
{
  __shared__ float s_sc[64], s_sh[64];
  int t = threadIdx.x;
  if (t < 64) {
    float n = (float)NPIX;
    float mean = ssum[t] / n;
    float var = ssq[t] / n - mean * mean;
    float sc = gamma[t] * rsqrtf(var + EPSf);
    s_sc[t] = sc;
    s_sh[t] = beta[t] - mean * sc;
  }
  __syncthreads();

  int p = blockIdx.x * 256 + t;
  int sp = p & 16383; int h = sp >> 7; int w = sp & 127;
  float off[NOFF];
  #pragma unroll
  for (int o = 0; o < NOFF; o++) off[o] = pw_b[o];
  const float4* dp = (const float4*)(DWT + (size_t)p * 64);
  #pragma unroll
  for (int c4 = 0; c4 < 16; c4++) {
    float4 d = dp[c4];
    int c = c4 * 4;
    float x0 = d.x * s_sc[c]     + s_sh[c];
    float x1 = d.y * s_sc[c + 1] + s_sh[c + 1];
    float x2 = d.z * s_sc[c + 2] + s_sh[c + 2];
    float x3 = d.w * s_sc[c + 3] + s_sh[c + 3];
    #pragma unroll
    for (int o = 0; o < NOFF; o++) {
      const float* pw = pw_w + o * 64 + c;
      off[o] += pw[0] * x0 + pw[1] * x1 + pw[2] * x2 + pw[3] * x3;
    }
  }
  #pragma unroll
  for (int kk = 0; kk < KKn; kk++) {
    float py = (float)h - 1.f + (float)(kk / 3) + off[2 * kk];
    float px = (float)w - 1.f + (float)(kk % 3) + off[2 * kk + 1];
    float2* g = (float2*)(GEOM2 + ((size_t)kk * NPIX + p) * 2);
    *g = make_float2(py, px);
  }
}

// ---------------------------------------------------------------------------
// K4v5: wave = 16 px x 64 o (4 n-tiles). Block = 64 contiguous px (half-row).
// No cross-wave gather duplication. Depth-1 software pipeline over kk.
__global__ __launch_bounds__(256) void k4_mfma5(
    const unsigned short* __restrict__ XTH, const float* __restrict__ DWT,
    const float* __restrict__ GEOM2, const unsigned short* __restrict__ WT2,
    const float* __restrict__ ssum, const float* __restrict__ ssq,
    const float* __restrict__ gamma, const float* __restrict__ beta,
    const float* __restrict__ deform_b, const float* __restrict__ skip_scale,
    float* __restrict__ out)
{
  __shared__ float s_sc[64], s_sh[64];
  const int tid = threadIdx.x;
  if (tid < 64) {
    float n = (float)NPIX;
    float mean = ssum[tid] / n;
    float var = ssq[tid] / n - mean * mean;
    float sc = gamma[tid] * rsqrtf(var + EPSf);
    s_sc[tid] = sc;
    s_sh[tid] = beta[tid] - mean * sc;
  }
  __syncthreads();

  const int lane = tid & 63;
  const int wv = tid >> 6;
  const int l15 = lane & 15;
  const int lg = lane >> 4;
  const int bid = blockIdx.x;
  const int swz = (bid & 7) * 128 + (bid >> 3);   // 1024 % 8 == 0 -> bijective
  const int p0 = swz * 64;
  const int b = p0 >> 14;
  const int pw0 = p0 + wv * 16;                   // wave's 16 pixels
  const int c8 = lg * 8;

  float4v acc0 = {0.f,0.f,0.f,0.f}, acc1 = {0.f,0.f,0.f,0.f};
  float4v acc2 = {0.f,0.f,0.f,0.f}, acc3 = {0.f,0.f,0.f,0.f};

  const unsigned short* xb = XTH + (size_t)b * HWn * 64;

  float2 g_n = *(const float2*)(GEOM2 + ((size_t)0 * NPIX + pw0 + l15) * 2);
  float cm00, cm01, cm10, cm11, nm00, nm01, nm10, nm11;
  const unsigned short *pb00, *pb01, *pb10, *pb11;
  ushort8v c0a,c0b,c0c,c0d, c1a,c1b,c1c,c1d;
  ushort8v n0a,n0b,n0c,n0d, n1a,n1b,n1c,n1d;

  // prologue: gathers for kk=0
  MKADDR(g_n, pb00, pb01, pb10, pb11, cm00, cm01, cm10, cm11);
  c0a = *(const ushort8v*)(pb00 + c8);      c0b = *(const ushort8v*)(pb01 + c8);
  c0c = *(const ushort8v*)(pb10 + c8);      c0d = *(const ushort8v*)(pb11 + c8);
  c1a = *(const ushort8v*)(pb00 + 32 + c8); c1b = *(const ushort8v*)(pb01 + 32 + c8);
  c1c = *(const ushort8v*)(pb10 + 32 + c8); c1d = *(const ushort8v*)(pb11 + 32 + c8);
  g_n = *(const float2*)(GEOM2 + ((size_t)1 * NPIX + pw0 + l15) * 2);

  #pragma unroll
  for (int kk = 0; kk < KKn; kk++) {
    // issue next-kk gathers before touching current data
    if (kk < 8) {
      MKADDR(g_n, pb00, pb01, pb10, pb11, nm00, nm01, nm10, nm11);
      n0a = *(const ushort8v*)(pb00 + c8);      n0b = *(const ushort8v*)(pb01 + c8);
      n0c = *(const ushort8v*)(pb10 + c8);      n0d = *(const ushort8v*)(pb11 + c8);
      n1a = *(const ushort8v*)(pb00 + 32 + c8); n1b = *(const ushort8v*)(pb01 + 32 + c8);
      n1c = *(const ushort8v*)(pb10 + 32 + c8); n1d = *(const ushort8v*)(pb11 + 32 + c8);
    }
    // blend both 32-ch chunks into A-fragments (used by all 4 n-tiles)
    short8v af0, af1;
    #pragma unroll
    for (int j = 0; j < 8; j++) {
      float s0 = b2f(c0a[j]) * cm00 + b2f(c0b[j]) * cm01 +
                 b2f(c0c[j]) * cm10 + b2f(c0d[j]) * cm11;
      af0[j] = (short)f2bf(s0);
      float s1 = b2f(c1a[j]) * cm00 + b2f(c1b[j]) * cm01 +
                 b2f(c1c[j]) * cm10 + b2f(c1d[j]) * cm11;
      af1[j] = (short)f2bf(s1);
    }
    // 4 n-tiles x 2 chunks of MFMA
    const unsigned short* wtkk = WT2 + (size_t)kk * 4096 + (size_t)l15 * 64 + c8;
    {
      short8v ba = *(const short8v*)(wtkk);
      short8v bb = *(const short8v*)(wtkk + 32);
      acc0 = __builtin_amdgcn_mfma_f32_16x16x32_bf16(af0, ba, acc0, 0, 0, 0);
      acc0 = __builtin_amdgcn_mfma_f32_16x16x32_bf16(af1, bb, acc0, 0, 0, 0);
    }
    {
      short8v ba = *(const short8v*)(wtkk + 16 * 64);
      short8v bb = *(const short8v*)(wtkk + 16 * 64 + 32);
      acc1 = __builtin_amdgcn_mfma_f32_16x16x32_bf16(af0, ba, acc1, 0, 0, 0);
      acc1 = __builtin_amdgcn_mfma_f32_16x16x32_bf16(af1, bb, acc1, 0, 0, 0);
    }
    {
      short8v ba = *(const short8v*)(wtkk + 32 * 64);
      short8v bb = *(const short8v*)(wtkk + 32 * 64 + 32);
      acc2 = __builtin_amdgcn_mfma_f32_16x16x32_bf16(af0, ba, acc2, 0, 0, 0);
      acc2 = __builtin_amdgcn_mfma_f32_16x16x32_bf16(af1, bb, acc2, 0, 0, 0);
    }
    {
      short8v ba = *(const short8v*)(wtkk + 48 * 64);
      short8v bb = *(const short8v*)(wtkk + 48 * 64 + 32);
      acc3 = __builtin_amdgcn_mfma_f32_16x16x32_bf16(af0, ba, acc3, 0, 0, 0);
      acc3 = __builtin_amdgcn_mfma_f32_16x16x32_bf16(af1, bb, acc3, 0, 0, 0);
    }
    // rotate pipeline registers
    if (kk < 8) {
      cm00 = nm00; cm01 = nm01; cm10 = nm10; cm11 = nm11;
      c0a = n0a; c0b = n0b; c0c = n0c; c0d = n0d;
      c1a = n1a; c1b = n1b; c1c = n1c; c1d = n1d;
      if (kk < 7)
        g_n = *(const float2*)(GEOM2 + ((size_t)(kk + 2) * NPIX + pw0 + l15) * 2);
    }
  }

  // Epilogue: out[b][o][sp] = acc + deform_b + BN(DWT) + XTH*skip
  float sk = skip_scale[0];
  #pragma unroll
  for (int nt = 0; nt < 4; nt++) {
    int o = nt * 16 + l15;
    float sc = s_sc[o], sh = s_sh[o], db = deform_b[o];
    float* outb = out + ((size_t)(b * 64 + o)) * HWn;
    float4v a = (nt == 0) ? acc0 : (nt == 1) ? acc1 : (nt == 2) ? acc2 : acc3;
    #pragma unroll
    for (int r = 0; r < 4; r++) {
      int p = pw0 + lg * 4 + r;
      int sp = p & 16383;
      float dv = DWT[(size_t)p * 64 + o];
      float xv = b2f(XTH[(size_t)p * 64 + o]);
      outb[sp] = a[r] + db + dv * sc + sh + xv * sk;
    }
  }
}

// ---------------------------------------------------------------------------
extern "C" void kernel_launch(void* const* d_in, const int* in_sizes, int n_in,
                              void* d_out, int out_size, void* d_ws, size_t ws_size,
                              hipStream_t stream)
{
  const float* x        = (const float*)d_in[0];
  const float* dw_w     = (const float*)d_in[1];
  const float* dw_b     = (const float*)d_in[2];
  const float* bn_gamma = (const float*)d_in[3];
  const float* bn_beta  = (const float*)d_in[4];
  const float* pw_w     = (const float*)d_in[5];
  const float* pw_b     = (const float*)d_in[6];
  const float* skip     = (const float*)d_in[7];
  const float* deform_w = (const float*)d_in[8];
  const float* deform_b = (const float*)d_in[9];
  float* out = (float*)d_out;
  float* ws  = (float*)d_ws;

  unsigned short* XTH = (unsigned short*)(ws + OFF_XTH);
  unsigned short* WT2 = (unsigned short*)(ws + OFF_WT);

  hipMemsetAsync(ws + OFF_SSUM, 0, 2 * 64 * sizeof(float), stream);

  k_wt<<<144, 256, 0, stream>>>(deform_w, WT2);
  k1_dw_t4<<<1024, 256, 0, stream>>>(x, dw_w, dw_b, XTH, ws + OFF_DWT,
                                     ws + OFF_SSUM, ws + OFF_SSQ);
  k3_offsets2<<<256, 256, 0, stream>>>(ws + OFF_DWT, ws + OFF_SSUM, ws + OFF_SSQ,
                                       bn_gamma, bn_beta, pw_w, pw_b, ws + OFF_GEOM);
  k4_mfma5<<<1024, 256, 0, stream>>>(XTH, ws + OFF_DWT, ws + OFF_GEOM, WT2,
                                     ws + OFF_SSUM, ws + OFF_SSQ, bn_gamma, bn_beta,
                                     deform_b, skip, out);
}